// Round 1
// baseline (263.249 us; speedup 1.0000x reference)
//
#include <hip/hip_runtime.h>
#include <math.h>

#define NPTS   131072
#define INF    512
#define ROWF   513      // 512 features + 1 cid column
#define NCASE  64
#define HID    512

// ---------------------------------------------------------------------------
// K1: per-case partial sums over a point-chunk for one 128-feature slice.
// grid (chunks, 4 slices), block 128 threads (thread t owns feature slice*128+t).
// No atomics on the feature accumulation: exclusive LDS column per thread.
// ---------------------------------------------------------------------------
__global__ __launch_bounds__(128)
void k1_partial(const float* __restrict__ x, float* __restrict__ psum,
                float* __restrict__ pcnt, int* __restrict__ cids,
                int ppc) {
  __shared__ float acc[NCASE * 128];   // 32 KB
  __shared__ int   cidl[512];          // 2 KB
  __shared__ int   cntl[NCASE];

  const int t     = threadIdx.x;
  const int chunk = blockIdx.x;
  const int slice = blockIdx.y;

  for (int i = t; i < NCASE * 128; i += 128) acc[i] = 0.f;
  if (t < NCASE) cntl[t] = 0;

  const int base = chunk * ppc;

  for (int tile = 0; tile < ppc; tile += 512) {
    __syncthreads();
    // stage cids for this tile (and counts / global cid cache on slice 0)
    for (int i = t; i < 512; i += 128) {
      float cf = x[(size_t)(base + tile + i) * ROWF + INF];
      int c = (int)(cf + 0.5f);
      cidl[i] = c;
      if (slice == 0) {
        atomicAdd(&cntl[c], 1);
        cids[base + tile + i] = c;
      }
    }
    __syncthreads();

    const float* gx = x + (size_t)(base + tile) * ROWF + slice * 128 + t;
    #pragma unroll 1
    for (int p = 0; p < 512; p += 8) {
      float v[8];
      #pragma unroll
      for (int j = 0; j < 8; ++j) v[j] = gx[(size_t)(p + j) * ROWF];
      #pragma unroll
      for (int j = 0; j < 8; ++j) acc[cidl[p + j] * 128 + t] += v[j];
    }
  }
  __syncthreads();

  // write partials: layout ((chunk*4+slice)*64 + c)*128 + f
  float* od = psum + (size_t)(chunk * 4 + slice) * NCASE * 128;
  for (int c = 0; c < NCASE; ++c) od[c * 128 + t] = acc[c * 128 + t];
  if (slice == 0 && t < NCASE) pcnt[chunk * NCASE + t] = (float)cntl[t];
}

// ---------------------------------------------------------------------------
// K2: reduce partial sums over chunks, divide by counts -> h0 (64 x 512)
// grid 128 blocks x 256 threads; one thread per output element.
// ---------------------------------------------------------------------------
__global__ __launch_bounds__(256)
void k2_reduce(const float* __restrict__ psum, const float* __restrict__ pcnt,
               float* __restrict__ h0, int chunks) {
  __shared__ float cs[256];
  const int t  = threadIdx.x;
  const int e  = blockIdx.x * 256 + t;
  const int c  = e >> 9;         // case (constant within a block)
  const int fg = e & 511;
  const int slice = fg >> 7;
  const int f     = fg & 127;

  const size_t stride = (size_t)4 * NCASE * 128;
  const float* p = psum + ((size_t)slice * NCASE + c) * 128 + f;
  float s = 0.f;
  for (int k = 0; k < chunks; ++k) s += p[(size_t)k * stride];

  float cv = (t < chunks) ? pcnt[(size_t)t * NCASE + c] : 0.f;
  cs[t] = cv;
  __syncthreads();
  for (int w = 128; w > 0; w >>= 1) {
    if (t < w) cs[t] += cs[t + w];
    __syncthreads();
  }
  float cnt = fmaxf(cs[0], 1.f);
  h0[e] = s / cnt;
}

// ---------------------------------------------------------------------------
// K_scale: scale[row] = g[row] / ||V[row]||  (row length K=512)
// ---------------------------------------------------------------------------
__global__ __launch_bounds__(256)
void k_scale(const float* __restrict__ V, const float* __restrict__ g,
             float* __restrict__ scale, int K) {
  __shared__ float red[256];
  const int row = blockIdx.x;
  const int t   = threadIdx.x;
  const float* vr = V + (size_t)row * K;
  float s = 0.f;
  for (int k = t; k < K; k += 256) { float v = vr[k]; s += v * v; }
  red[t] = s;
  __syncthreads();
  for (int w = 128; w > 0; w >>= 1) {
    if (t < w) red[t] += red[t + w];
    __syncthreads();
  }
  if (t == 0) scale[row] = g[row] / sqrtf(red[0]);
}

// ---------------------------------------------------------------------------
// K_layer: hout[n][o] = act( scale[o]*dot(hin[n], W[o]) + bias[o] )
// grid (2, 64), block 256: one thread per output element.
// ---------------------------------------------------------------------------
template <bool SILU, bool SCALED>
__global__ __launch_bounds__(256)
void k_layer(const float* __restrict__ hin, const float* __restrict__ W,
             const float* __restrict__ scale, const float* __restrict__ bias,
             float* __restrict__ hout) {
  const int n = blockIdx.y;
  const int o = blockIdx.x * 256 + threadIdx.x;
  const float* hr = hin + (size_t)n * HID;
  const float* wr = W + (size_t)o * HID;
  float s0 = 0.f, s1 = 0.f, s2 = 0.f, s3 = 0.f;
  for (int k = 0; k < HID; k += 4) {
    s0 += hr[k + 0] * wr[k + 0];
    s1 += hr[k + 1] * wr[k + 1];
    s2 += hr[k + 2] * wr[k + 2];
    s3 += hr[k + 3] * wr[k + 3];
  }
  float s = (s0 + s1) + (s2 + s3);
  float y = SCALED ? (s * scale[o] + bias[o]) : (s + bias[o]);
  if (SILU) y = y / (1.f + expf(-y));
  hout[(size_t)n * HID + o] = y;
}

// ---------------------------------------------------------------------------
// K_scatter: out[p][:] = h3[cid[p]][:]   (float4 stores)
// one thread per float4 of output; grid 65536 x 256.
// ---------------------------------------------------------------------------
__global__ __launch_bounds__(256)
void k_scatter(const int* __restrict__ cids, const float* __restrict__ h3,
               float* __restrict__ out) {
  const size_t g = (size_t)blockIdx.x * 256 + threadIdx.x;  // float4 index
  const int p = (int)(g >> 7);   // 128 float4 per 512-float row
  const int q = (int)(g & 127);
  const int c = cids[p];
  const float4* hv = (const float4*)(h3 + (size_t)c * HID);
  reinterpret_cast<float4*>(out)[g] = hv[q];
}

// ---------------------------------------------------------------------------
extern "C" void kernel_launch(void* const* d_in, const int* in_sizes, int n_in,
                              void* d_out, int out_size, void* d_ws, size_t ws_size,
                              hipStream_t stream) {
  const float* x  = (const float*)d_in[0];
  const float* V0 = (const float*)d_in[1];
  const float* g0 = (const float*)d_in[2];
  const float* b0 = (const float*)d_in[3];
  const float* V1 = (const float*)d_in[4];
  const float* g1 = (const float*)d_in[5];
  const float* b1 = (const float*)d_in[6];
  const float* Wf = (const float*)d_in[7];
  const float* bf = (const float*)d_in[8];
  float* out = (float*)d_out;
  float* ws  = (float*)d_ws;

  // choose chunk count so partials fit in workspace
  int chunks = 256;
  while (chunks > 32) {
    size_t need_f = (size_t)chunks * 32768 + (size_t)chunks * 64
                  + 4 * 32768 + 1024 + NPTS;
    if (need_f * sizeof(float) <= ws_size) break;
    chunks >>= 1;
  }
  const int ppc = NPTS / chunks;

  size_t off = 0;
  float* psum   = ws + off; off += (size_t)chunks * 32768;
  float* pcnt   = ws + off; off += (size_t)chunks * 64;
  float* h0     = ws + off; off += 32768;
  float* h1     = ws + off; off += 32768;
  float* h2     = ws + off; off += 32768;
  float* h3     = ws + off; off += 32768;
  float* scale0 = ws + off; off += 512;
  float* scale1 = ws + off; off += 512;
  int*   cids   = (int*)(ws + off); off += NPTS;

  k1_partial<<<dim3(chunks, 4), dim3(128), 0, stream>>>(x, psum, pcnt, cids, ppc);
  k2_reduce<<<dim3(128), dim3(256), 0, stream>>>(psum, pcnt, h0, chunks);
  k_scale<<<dim3(512), dim3(256), 0, stream>>>(V0, g0, scale0, HID);
  k_scale<<<dim3(512), dim3(256), 0, stream>>>(V1, g1, scale1, HID);
  k_layer<true,  true ><<<dim3(2, 64), dim3(256), 0, stream>>>(h0, V0, scale0, b0, h1);
  k_layer<true,  true ><<<dim3(2, 64), dim3(256), 0, stream>>>(h1, V1, scale1, b1, h2);
  k_layer<false, false><<<dim3(2, 64), dim3(256), 0, stream>>>(h2, Wf, nullptr, bf, h3);
  k_scatter<<<dim3(NPTS * 128 / 256), dim3(256), 0, stream>>>(cids, h3, out);
}

// Round 2
// 235.404 us; speedup vs baseline: 1.1183x; 1.1183x over previous
//
#include <hip/hip_runtime.h>
#include <math.h>

#define NPTS   131072
#define INF    512
#define ROWF   513      // 512 features + 1 cid column
#define NCASE  64
#define HID    512
#define NB     256      // histogram blocks
#define CHUNK  512      // points per histogram block
#define SEG    16       // segments per case for sum/scatter

// ---------------------------------------------------------------------------
// K_hist: per-block cid histogram (int LDS atomics -> deterministic) + cid cache
// ---------------------------------------------------------------------------
__global__ __launch_bounds__(256)
void k_hist(const float* __restrict__ x, int* __restrict__ hist,
            int* __restrict__ cids) {
  __shared__ int h[NCASE];
  const int t = threadIdx.x;
  const int b = blockIdx.x;
  if (t < NCASE) h[t] = 0;
  __syncthreads();
  const int base = b * CHUNK;
  for (int i = t; i < CHUNK; i += 256) {
    float cf = x[(size_t)(base + i) * ROWF + INF];
    int c = (int)(cf + 0.5f);
    cids[base + i] = c;
    atomicAdd(&h[c], 1);
  }
  __syncthreads();
  if (t < NCASE) hist[b * NCASE + t] = h[t];
}

// ---------------------------------------------------------------------------
// K_scan: per-(block,case) exclusive offsets (relative), case totals, case bases.
// One wave; thread c owns case c. All integer -> deterministic.
// ---------------------------------------------------------------------------
__global__ __launch_bounds__(64)
void k_scan(const int* __restrict__ hist, int* __restrict__ rel,
            int* __restrict__ base, int* __restrict__ cnt,
            float* __restrict__ cntf) {
  __shared__ int lcnt[NCASE];
  __shared__ int lbase[NCASE];
  const int c = threadIdx.x;
  int running = 0;
  for (int b = 0; b < NB; ++b) {
    rel[b * NCASE + c] = running;
    running += hist[b * NCASE + c];
  }
  lcnt[c] = running;
  cnt[c] = running;
  cntf[c] = (float)running;
  __syncthreads();
  if (c == 0) {
    int acc = 0;
    for (int i = 0; i < NCASE; ++i) { lbase[i] = acc; acc += lcnt[i]; }
  }
  __syncthreads();
  base[c] = lbase[c];
}

// ---------------------------------------------------------------------------
// K_build: emit per-case point-index lists in point-index order (deterministic).
// One wave per 512-point chunk; lane c handles case c.
// ---------------------------------------------------------------------------
__global__ __launch_bounds__(64)
void k_build(const int* __restrict__ cids, const int* __restrict__ rel,
             const int* __restrict__ base, int* __restrict__ idxlist) {
  __shared__ int cidl[CHUNK];
  const int lane = threadIdx.x;
  const int b = blockIdx.x;
  for (int i = lane; i < CHUNK; i += 64) cidl[i] = cids[b * CHUNK + i];
  __syncthreads();
  int myoff = rel[b * NCASE + lane] + base[lane];
  int rank = 0;
  for (int i = 0; i < CHUNK; ++i) {
    if (cidl[i] == lane) { idxlist[myoff + rank] = b * CHUNK + i; ++rank; }
  }
}

// ---------------------------------------------------------------------------
// K_sum: register-accumulated segment sums. grid (SEG, NCASE), block 128.
// Thread t owns features {t, t+128, t+256, t+384}; coalesced 256B loads.
// ---------------------------------------------------------------------------
__global__ __launch_bounds__(128)
void k_sum(const float* __restrict__ x, const int* __restrict__ idxlist,
           const int* __restrict__ base, const int* __restrict__ cnt,
           float* __restrict__ psum) {
  const int t = threadIdx.x;
  const int s = blockIdx.x;
  const int c = blockIdx.y;
  const int n = cnt[c];
  const int bs = base[c];
  int p0 = (s * n) / SEG;
  int p1 = ((s + 1) * n) / SEG;

  float a0 = 0.f, a1 = 0.f, a2 = 0.f, a3 = 0.f;
  int p = p0;
  for (; p + 4 <= p1; p += 4) {
    int i0 = __builtin_amdgcn_readfirstlane(idxlist[bs + p + 0]);
    int i1 = __builtin_amdgcn_readfirstlane(idxlist[bs + p + 1]);
    int i2 = __builtin_amdgcn_readfirstlane(idxlist[bs + p + 2]);
    int i3 = __builtin_amdgcn_readfirstlane(idxlist[bs + p + 3]);
    const float* r0 = x + (size_t)i0 * ROWF + t;
    const float* r1 = x + (size_t)i1 * ROWF + t;
    const float* r2 = x + (size_t)i2 * ROWF + t;
    const float* r3 = x + (size_t)i3 * ROWF + t;
    float v00 = r0[0], v01 = r0[128], v02 = r0[256], v03 = r0[384];
    float v10 = r1[0], v11 = r1[128], v12 = r1[256], v13 = r1[384];
    float v20 = r2[0], v21 = r2[128], v22 = r2[256], v23 = r2[384];
    float v30 = r3[0], v31 = r3[128], v32 = r3[256], v33 = r3[384];
    a0 += v00; a1 += v01; a2 += v02; a3 += v03;
    a0 += v10; a1 += v11; a2 += v12; a3 += v13;
    a0 += v20; a1 += v21; a2 += v22; a3 += v23;
    a0 += v30; a1 += v31; a2 += v32; a3 += v33;
  }
  for (; p < p1; ++p) {
    int i0 = __builtin_amdgcn_readfirstlane(idxlist[bs + p]);
    const float* r0 = x + (size_t)i0 * ROWF + t;
    a0 += r0[0]; a1 += r0[128]; a2 += r0[256]; a3 += r0[384];
  }
  float* od = psum + ((size_t)c * SEG + s) * HID;
  od[t] = a0; od[t + 128] = a1; od[t + 256] = a2; od[t + 384] = a3;
}

// ---------------------------------------------------------------------------
// K_h0: reduce segments, divide by count. grid 64 blocks x 512 threads.
// ---------------------------------------------------------------------------
__global__ __launch_bounds__(512)
void k_h0(const float* __restrict__ psum, const float* __restrict__ cntf,
          float* __restrict__ h0) {
  const int c = blockIdx.x;
  const int f = threadIdx.x;
  float s = 0.f;
  for (int seg = 0; seg < SEG; ++seg) s += psum[((size_t)c * SEG + seg) * HID + f];
  h0[(size_t)c * HID + f] = s / fmaxf(cntf[c], 1.f);
}

// ---------------------------------------------------------------------------
// K_scale: scale[row] = g[row] / ||V[row]||
// ---------------------------------------------------------------------------
__global__ __launch_bounds__(256)
void k_scale(const float* __restrict__ V, const float* __restrict__ g,
             float* __restrict__ scale, int K) {
  __shared__ float red[256];
  const int row = blockIdx.x;
  const int t   = threadIdx.x;
  const float* vr = V + (size_t)row * K;
  float s = 0.f;
  for (int k = t; k < K; k += 256) { float v = vr[k]; s += v * v; }
  red[t] = s;
  __syncthreads();
  for (int w = 128; w > 0; w >>= 1) {
    if (t < w) red[t] += red[t + w];
    __syncthreads();
  }
  if (t == 0) scale[row] = g[row] / sqrtf(red[0]);
}

// ---------------------------------------------------------------------------
// K_layer: hout[n][o] = act( scale[o]*dot(hin[n], W[o]) + bias[o] )
// ---------------------------------------------------------------------------
template <bool SILU, bool SCALED>
__global__ __launch_bounds__(256)
void k_layer(const float* __restrict__ hin, const float* __restrict__ W,
             const float* __restrict__ scale, const float* __restrict__ bias,
             float* __restrict__ hout) {
  const int n = blockIdx.y;
  const int o = blockIdx.x * 256 + threadIdx.x;
  const float* hr = hin + (size_t)n * HID;
  const float* wr = W + (size_t)o * HID;
  float s0 = 0.f, s1 = 0.f, s2 = 0.f, s3 = 0.f;
  for (int k = 0; k < HID; k += 4) {
    s0 += hr[k + 0] * wr[k + 0];
    s1 += hr[k + 1] * wr[k + 1];
    s2 += hr[k + 2] * wr[k + 2];
    s3 += hr[k + 3] * wr[k + 3];
  }
  float s = (s0 + s1) + (s2 + s3);
  float y = SCALED ? (s * scale[o] + bias[o]) : (s + bias[o]);
  if (SILU) y = y / (1.f + expf(-y));
  hout[(size_t)n * HID + o] = y;
}

// ---------------------------------------------------------------------------
// K_scatter: list-driven broadcast; h3 row in registers, pure float4 stores.
// grid (SEG, NCASE), block 256 (two waves-pairs -> two points in flight).
// ---------------------------------------------------------------------------
__global__ __launch_bounds__(256)
void k_scatter(const int* __restrict__ idxlist, const int* __restrict__ base,
               const int* __restrict__ cnt, const float* __restrict__ h3,
               float* __restrict__ out) {
  const int t = threadIdx.x;
  const int s = blockIdx.x;
  const int c = blockIdx.y;
  const int n = cnt[c];
  const int bs = base[c];
  int p0 = (s * n) / SEG;
  int p1 = ((s + 1) * n) / SEG;
  const int q = t & 127;
  const int which = t >> 7;
  float4 hv = ((const float4*)(h3 + (size_t)c * HID))[q];
  for (int p = p0 + which; p < p1; p += 2) {
    int idx = __builtin_amdgcn_readfirstlane(idxlist[bs + p]);
    ((float4*)(out + (size_t)idx * HID))[q] = hv;
  }
}

// ---------------------------------------------------------------------------
extern "C" void kernel_launch(void* const* d_in, const int* in_sizes, int n_in,
                              void* d_out, int out_size, void* d_ws, size_t ws_size,
                              hipStream_t stream) {
  const float* x  = (const float*)d_in[0];
  const float* V0 = (const float*)d_in[1];
  const float* g0 = (const float*)d_in[2];
  const float* b0 = (const float*)d_in[3];
  const float* V1 = (const float*)d_in[4];
  const float* g1 = (const float*)d_in[5];
  const float* b1 = (const float*)d_in[6];
  const float* Wf = (const float*)d_in[7];
  const float* bf = (const float*)d_in[8];
  float* out = (float*)d_out;
  float* ws  = (float*)d_ws;

  size_t off = 0;
  float* psum   = ws + off; off += (size_t)NCASE * SEG * HID;   // 524288
  float* h0     = ws + off; off += NCASE * HID;
  float* h1     = ws + off; off += NCASE * HID;
  float* h2     = ws + off; off += NCASE * HID;
  float* h3     = ws + off; off += NCASE * HID;
  float* scale0 = ws + off; off += 512;
  float* scale1 = ws + off; off += 512;
  float* cntf   = ws + off; off += 64;
  int* iws = (int*)(ws + off);
  size_t ioff = 0;
  int* hist    = iws + ioff; ioff += NB * NCASE;
  int* rel     = iws + ioff; ioff += NB * NCASE;
  int* basec   = iws + ioff; ioff += NCASE;
  int* cnt     = iws + ioff; ioff += NCASE;
  int* cids    = iws + ioff; ioff += NPTS;
  int* idxlist = iws + ioff; ioff += NPTS;

  k_hist <<<dim3(NB), dim3(256), 0, stream>>>(x, hist, cids);
  k_scan <<<dim3(1), dim3(64), 0, stream>>>(hist, rel, basec, cnt, cntf);
  k_build<<<dim3(NB), dim3(64), 0, stream>>>(cids, rel, basec, idxlist);
  k_sum  <<<dim3(SEG, NCASE), dim3(128), 0, stream>>>(x, idxlist, basec, cnt, psum);
  k_h0   <<<dim3(NCASE), dim3(512), 0, stream>>>(psum, cntf, h0);
  k_scale<<<dim3(512), dim3(256), 0, stream>>>(V0, g0, scale0, HID);
  k_scale<<<dim3(512), dim3(256), 0, stream>>>(V1, g1, scale1, HID);
  k_layer<true,  true ><<<dim3(2, NCASE), dim3(256), 0, stream>>>(h0, V0, scale0, b0, h1);
  k_layer<true,  true ><<<dim3(2, NCASE), dim3(256), 0, stream>>>(h1, V1, scale1, b1, h2);
  k_layer<false, false><<<dim3(2, NCASE), dim3(256), 0, stream>>>(h2, Wf, nullptr, bf, h3);
  k_scatter<<<dim3(SEG, NCASE), dim3(256), 0, stream>>>(idxlist, basec, cnt, h3, out);
}

// Round 3
// 233.169 us; speedup vs baseline: 1.1290x; 1.0096x over previous
//
#include <hip/hip_runtime.h>
#include <math.h>

#define NPTS   131072
#define INF    512
#define ROWF   513      // 512 features + 1 cid column
#define NCASE  64
#define HID    512
#define NB     256      // histogram chunks
#define CHUNK  512      // points per chunk
#define SEG    32       // segments per case for k_sum

// ---------------------------------------------------------------------------
// K_hist: per-chunk cid histogram (LDS int atomics -> deterministic) + cid cache.
// hist stored transposed: hist[c*NB + b] so k_scan reads coalesced.
// ---------------------------------------------------------------------------
__global__ __launch_bounds__(256)
void k_hist(const float* __restrict__ x, int* __restrict__ hist,
            int* __restrict__ cids) {
  __shared__ int h[NCASE];
  const int t = threadIdx.x;
  const int b = blockIdx.x;
  if (t < NCASE) h[t] = 0;
  __syncthreads();
  const int base = b * CHUNK;
  for (int i = t; i < CHUNK; i += 256) {
    float cf = x[(size_t)(base + i) * ROWF + INF];
    int c = (int)(cf + 0.5f);
    cids[base + i] = c;
    atomicAdd(&h[c], 1);
  }
  __syncthreads();
  if (t < NCASE) hist[t * NB + b] = h[t];
}

// ---------------------------------------------------------------------------
// K_scan: per-case parallel exclusive scan over the 256 chunk histograms.
// 64 blocks (one per case) x 256 threads (one per chunk).
// ---------------------------------------------------------------------------
__global__ __launch_bounds__(256)
void k_scan(const int* __restrict__ hist, int* __restrict__ rel,
            int* __restrict__ cnt) {
  __shared__ int buf[NB];
  const int c = blockIdx.x;
  const int t = threadIdx.x;
  const int v = hist[c * NB + t];
  buf[t] = v;
  __syncthreads();
  for (int d = 1; d < NB; d <<= 1) {
    int u = (t >= d) ? buf[t - d] : 0;
    __syncthreads();
    buf[t] += u;
    __syncthreads();
  }
  rel[t * NCASE + c] = buf[t] - v;          // exclusive within case
  if (t == NB - 1) cnt[c] = buf[t];
}

// ---------------------------------------------------------------------------
// K_build: emit per-case point lists in point order (deterministic).
// base[c] computed on the fly by a 64-lane wave scan of cnt.
// ---------------------------------------------------------------------------
__global__ __launch_bounds__(64)
void k_build(const int* __restrict__ cids, const int* __restrict__ rel,
             const int* __restrict__ cnt, int* __restrict__ idxlist) {
  __shared__ int cidl[CHUNK];
  const int lane = threadIdx.x;
  const int b = blockIdx.x;
  for (int i = lane; i < CHUNK; i += 64) cidl[i] = cids[b * CHUNK + i];
  int lv = cnt[lane];
  int sc = lv;
  for (int d = 1; d < 64; d <<= 1) {
    int u = __shfl_up(sc, d, 64);
    if (lane >= d) sc += u;
  }
  const int base = sc - lv;                 // exclusive scan of cnt
  __syncthreads();
  int myoff = rel[b * NCASE + lane] + base;
  int rank = 0;
  for (int i = 0; i < CHUNK; ++i) {
    if (cidl[i] == lane) { idxlist[myoff + rank] = b * CHUNK + i; ++rank; }
  }
}

// ---------------------------------------------------------------------------
// K_sum: register-accumulated segment sums, 8 rows in flight.
// grid (SEG, NCASE), block 128; thread t owns features {t,t+128,t+256,t+384}.
// ---------------------------------------------------------------------------
__global__ __launch_bounds__(128)
void k_sum(const float* __restrict__ x, const int* __restrict__ idxlist,
           const int* __restrict__ cnt, float* __restrict__ psum) {
  const int t = threadIdx.x;
  const int s = blockIdx.x;
  const int c = blockIdx.y;
  const int lane = t & 63;

  int lv = cnt[lane];
  int sc = lv;
  for (int d = 1; d < 64; d <<= 1) {
    int u = __shfl_up(sc, d, 64);
    if (lane >= d) sc += u;
  }
  const int bs = __shfl(sc - lv, c, 64);    // base[c]
  const int n  = __shfl(lv, c, 64);         // cnt[c]

  int p0 = (s * n) / SEG;
  int p1 = ((s + 1) * n) / SEG;

  float a0 = 0.f, a1 = 0.f, a2 = 0.f, a3 = 0.f;
  int p = p0;
  for (; p + 8 <= p1; p += 8) {
    int idx[8];
    #pragma unroll
    for (int j = 0; j < 8; ++j)
      idx[j] = __builtin_amdgcn_readfirstlane(idxlist[bs + p + j]);
    float v[8][4];
    #pragma unroll
    for (int j = 0; j < 8; ++j) {
      const float* r = x + (size_t)idx[j] * ROWF + t;
      v[j][0] = r[0]; v[j][1] = r[128]; v[j][2] = r[256]; v[j][3] = r[384];
    }
    #pragma unroll
    for (int j = 0; j < 8; ++j) {
      a0 += v[j][0]; a1 += v[j][1]; a2 += v[j][2]; a3 += v[j][3];
    }
  }
  for (; p < p1; ++p) {
    int i0 = __builtin_amdgcn_readfirstlane(idxlist[bs + p]);
    const float* r = x + (size_t)i0 * ROWF + t;
    a0 += r[0]; a1 += r[128]; a2 += r[256]; a3 += r[384];
  }
  float* od = psum + ((size_t)c * SEG + s) * HID;
  od[t] = a0; od[t + 128] = a1; od[t + 256] = a2; od[t + 384] = a3;
}

// ---------------------------------------------------------------------------
// K_scale2: scale[row] = g[row] / ||V[row]|| for both layers in one launch.
// ---------------------------------------------------------------------------
__global__ __launch_bounds__(256)
void k_scale2(const float* __restrict__ V0, const float* __restrict__ g0,
              const float* __restrict__ V1, const float* __restrict__ g1,
              float* __restrict__ scale0, float* __restrict__ scale1) {
  __shared__ float red[256];
  const int row = blockIdx.x;               // 0..1023
  const int t   = threadIdx.x;
  const bool first = row < 512;
  const int r = first ? row : row - 512;
  const float* vr = (first ? V0 : V1) + (size_t)r * HID;
  float s = 0.f;
  for (int k = t; k < HID; k += 256) { float v = vr[k]; s += v * v; }
  red[t] = s;
  __syncthreads();
  for (int w = 128; w > 0; w >>= 1) {
    if (t < w) red[t] += red[t + w];
    __syncthreads();
  }
  if (t == 0) {
    float g = first ? g0[r] : g1[r];
    (first ? scale0 : scale1)[r] = g / sqrtf(red[0]);
  }
}

// ---------------------------------------------------------------------------
// K_layer: hout[n][o] = act( scale[o]*dot(hrow, W[o]) + bias[o] ).
// REDUCE: hrow = (sum over SEG psum segments)/cnt (fused h0 computation).
// hrow staged in LDS; dot reads via float4 (ds_read_b128 broadcast).
// ---------------------------------------------------------------------------
template <bool SILU, bool SCALED, bool REDUCE>
__global__ __launch_bounds__(256)
void k_layer(const float* __restrict__ hin, const float* __restrict__ W,
             const float* __restrict__ scale, const float* __restrict__ bias,
             const int* __restrict__ cnt, float* __restrict__ hout) {
  __shared__ float hrow[HID];
  const int n = blockIdx.y;
  const int t = threadIdx.x;
  const int o = blockIdx.x * 256 + t;
  if (REDUCE) {
    float inv = 1.f / fmaxf((float)cnt[n], 1.f);
    for (int f = t; f < HID; f += 256) {
      float s = 0.f;
      for (int seg = 0; seg < SEG; ++seg)
        s += hin[((size_t)n * SEG + seg) * HID + f];
      hrow[f] = s * inv;
    }
  } else {
    for (int f = t; f < HID; f += 256) hrow[f] = hin[(size_t)n * HID + f];
  }
  __syncthreads();
  const float* wr = W + (size_t)o * HID;
  float s0 = 0.f, s1 = 0.f, s2 = 0.f, s3 = 0.f;
  for (int k = 0; k < HID; k += 4) {
    float4 h4 = *(const float4*)&hrow[k];
    float4 w4 = *(const float4*)&wr[k];
    s0 += h4.x * w4.x; s1 += h4.y * w4.y;
    s2 += h4.z * w4.z; s3 += h4.w * w4.w;
  }
  float sdot = (s0 + s1) + (s2 + s3);
  float y = SCALED ? (sdot * scale[o] + bias[o]) : (sdot + bias[o]);
  if (SILU) y = y / (1.f + expf(-y));
  hout[(size_t)n * HID + o] = y;
}

// ---------------------------------------------------------------------------
// K_scatter: NATURAL-ORDER broadcast — fully sequential 2 KB row stores.
// Each block owns 64 contiguous points; h3 rows gathered from L2 (128 KB).
// ---------------------------------------------------------------------------
__global__ __launch_bounds__(256)
void k_scatter(const int* __restrict__ cids, const float* __restrict__ h3,
               float* __restrict__ out) {
  __shared__ int cl[64];
  const int t = threadIdx.x;
  const int q = t & 127;                    // float4 index in row
  const int half = t >> 7;
  const int base = blockIdx.x * 64;
  if (t < 64) cl[t] = cids[base + t];
  __syncthreads();
  #pragma unroll 4
  for (int p = half; p < 64; p += 2) {
    int c = cl[p];
    float4 hv = ((const float4*)(h3 + (size_t)c * HID))[q];
    ((float4*)(out + (size_t)(base + p) * HID))[q] = hv;
  }
}

// ---------------------------------------------------------------------------
extern "C" void kernel_launch(void* const* d_in, const int* in_sizes, int n_in,
                              void* d_out, int out_size, void* d_ws, size_t ws_size,
                              hipStream_t stream) {
  const float* x  = (const float*)d_in[0];
  const float* V0 = (const float*)d_in[1];
  const float* g0 = (const float*)d_in[2];
  const float* b0 = (const float*)d_in[3];
  const float* V1 = (const float*)d_in[4];
  const float* g1 = (const float*)d_in[5];
  const float* b1 = (const float*)d_in[6];
  const float* Wf = (const float*)d_in[7];
  const float* bf = (const float*)d_in[8];
  float* out = (float*)d_out;
  float* ws  = (float*)d_ws;

  size_t off = 0;
  float* psum   = ws + off; off += (size_t)NCASE * SEG * HID;   // 1 Mi floats
  float* h1     = ws + off; off += NCASE * HID;
  float* h2     = ws + off; off += NCASE * HID;
  float* h3     = ws + off; off += NCASE * HID;
  float* scale0 = ws + off; off += 512;
  float* scale1 = ws + off; off += 512;
  int* iws = (int*)(ws + off);
  size_t ioff = 0;
  int* hist    = iws + ioff; ioff += NCASE * NB;
  int* rel     = iws + ioff; ioff += NB * NCASE;
  int* cnt     = iws + ioff; ioff += NCASE;
  int* cids    = iws + ioff; ioff += NPTS;
  int* idxlist = iws + ioff; ioff += NPTS;

  k_scale2<<<dim3(1024), dim3(256), 0, stream>>>(V0, g0, V1, g1, scale0, scale1);
  k_hist  <<<dim3(NB), dim3(256), 0, stream>>>(x, hist, cids);
  k_scan  <<<dim3(NCASE), dim3(NB), 0, stream>>>(hist, rel, cnt);
  k_build <<<dim3(NB), dim3(64), 0, stream>>>(cids, rel, cnt, idxlist);
  k_sum   <<<dim3(SEG, NCASE), dim3(128), 0, stream>>>(x, idxlist, cnt, psum);
  k_layer<true,  true,  true ><<<dim3(2, NCASE), dim3(256), 0, stream>>>(psum, V0, scale0, b0, cnt, h1);
  k_layer<true,  true,  false><<<dim3(2, NCASE), dim3(256), 0, stream>>>(h1,   V1, scale1, b1, cnt, h2);
  k_layer<false, false, false><<<dim3(2, NCASE), dim3(256), 0, stream>>>(h2,   Wf, nullptr, bf, cnt, h3);
  k_scatter<<<dim3(NPTS / 64), dim3(256), 0, stream>>>(cids, h3, out);
}

// Round 5
// 199.980 us; speedup vs baseline: 1.3164x; 1.1660x over previous
//
#include <hip/hip_runtime.h>
#include <math.h>

#define NPTS   131072
#define INF    512
#define ROWF   513      // 512 features + 1 cid column
#define NCASE  64
#define HID    512
#define NB     256      // histogram chunks
#define CHUNK  512      // points per chunk
#define SEG    16       // segments per case for k_sum

typedef float v4f __attribute__((ext_vector_type(4)));

// ---------------------------------------------------------------------------
// K_hist: per-chunk cid histogram (LDS int atomics -> deterministic) + cid cache.
// hist stored transposed: hist[c*NB + b] so k_scan reads coalesced.
// ---------------------------------------------------------------------------
__global__ __launch_bounds__(256)
void k_hist(const float* __restrict__ x, int* __restrict__ hist,
            int* __restrict__ cids) {
  __shared__ int h[NCASE];
  const int t = threadIdx.x;
  const int b = blockIdx.x;
  if (t < NCASE) h[t] = 0;
  __syncthreads();
  const int base = b * CHUNK;
  for (int i = t; i < CHUNK; i += 256) {
    float cf = x[(size_t)(base + i) * ROWF + INF];
    int c = (int)(cf + 0.5f);
    cids[base + i] = c;
    atomicAdd(&h[c], 1);
  }
  __syncthreads();
  if (t < NCASE) hist[t * NB + b] = h[t];
}

// ---------------------------------------------------------------------------
// K_scan: per-case parallel exclusive scan over the 256 chunk histograms.
// ---------------------------------------------------------------------------
__global__ __launch_bounds__(256)
void k_scan(const int* __restrict__ hist, int* __restrict__ rel,
            int* __restrict__ cnt) {
  __shared__ int buf[NB];
  const int c = blockIdx.x;
  const int t = threadIdx.x;
  const int v = hist[c * NB + t];
  buf[t] = v;
  __syncthreads();
  for (int d = 1; d < NB; d <<= 1) {
    int u = (t >= d) ? buf[t - d] : 0;
    __syncthreads();
    buf[t] += u;
    __syncthreads();
  }
  rel[t * NCASE + c] = buf[t] - v;          // exclusive within case
  if (t == NB - 1) cnt[c] = buf[t];
}

// ---------------------------------------------------------------------------
// K_build: emit per-case point lists in point order (deterministic).
// ---------------------------------------------------------------------------
__global__ __launch_bounds__(64)
void k_build(const int* __restrict__ cids, const int* __restrict__ rel,
             const int* __restrict__ cnt, int* __restrict__ idxlist) {
  __shared__ int cidl[CHUNK];
  const int lane = threadIdx.x;
  const int b = blockIdx.x;
  for (int i = lane; i < CHUNK; i += 64) cidl[i] = cids[b * CHUNK + i];
  int lv = cnt[lane];
  int sc = lv;
  for (int d = 1; d < 64; d <<= 1) {
    int u = __shfl_up(sc, d, 64);
    if (lane >= d) sc += u;
  }
  const int base = sc - lv;                 // exclusive scan of cnt
  __syncthreads();
  int myoff = rel[b * NCASE + lane] + base;
  int rank = 0;
  for (int i = 0; i < CHUNK; ++i) {
    if (cidl[i] == lane) { idxlist[myoff + rank] = b * CHUNK + i; ++rank; }
  }
}

// ---------------------------------------------------------------------------
// K_sum: gather-sum with register-broadcast indices.
// grid (SEG, NCASE), block 128 (2 waves). Each wave covers all 512 features
// (8 per lane, stride-64 -> 256B coalesced segments per load instr).
// Indices: ONE coalesced load of 64 idx per wave-batch, then __shfl broadcast
// (register-only -> no vmcnt drain between points; loads stay in flight).
// ---------------------------------------------------------------------------
__global__ __launch_bounds__(128)
void k_sum(const float* __restrict__ x, const int* __restrict__ idxlist,
           const int* __restrict__ cnt, float* __restrict__ psum) {
  __shared__ float buf[2][HID];
  const int t = threadIdx.x;
  const int lane = t & 63;
  const int w = t >> 6;
  const int s = blockIdx.x;
  const int c = blockIdx.y;

  int lv = cnt[lane];
  int sc = lv;
  for (int d = 1; d < 64; d <<= 1) {
    int u = __shfl_up(sc, d, 64);
    if (lane >= d) sc += u;
  }
  const int bs = __shfl(sc - lv, c, 64);    // base[c]
  const int n  = __shfl(lv, c, 64);         // cnt[c]

  const int p0 = (s * n) / SEG;
  const int p1 = ((s + 1) * n) / SEG;
  const int m  = p1 - p0;

  float a[8];
  #pragma unroll
  for (int k = 0; k < 8; ++k) a[k] = 0.f;

  for (int j0 = w * 64; j0 < m; j0 += 128) {
    const int nb = (m - j0 < 64) ? (m - j0) : 64;
    int iv = (lane < nb) ? idxlist[bs + p0 + j0 + lane] : 0;
    int jj = 0;
    for (; jj + 4 <= nb; jj += 4) {
      float v[4][8];
      #pragma unroll
      for (int u = 0; u < 4; ++u) {
        int idx = __shfl(iv, jj + u, 64);
        const float* r = x + (size_t)idx * ROWF + lane;
        #pragma unroll
        for (int k = 0; k < 8; ++k) v[u][k] = __builtin_nontemporal_load(r + 64 * k);
      }
      #pragma unroll
      for (int u = 0; u < 4; ++u) {
        #pragma unroll
        for (int k = 0; k < 8; ++k) a[k] += v[u][k];
      }
    }
    for (; jj < nb; ++jj) {
      int idx = __shfl(iv, jj, 64);
      const float* r = x + (size_t)idx * ROWF + lane;
      #pragma unroll
      for (int k = 0; k < 8; ++k) a[k] += __builtin_nontemporal_load(r + 64 * k);
    }
  }

  #pragma unroll
  for (int k = 0; k < 8; ++k) buf[w][lane + 64 * k] = a[k];
  __syncthreads();
  float* od = psum + ((size_t)c * SEG + s) * HID;
  for (int f = t; f < HID; f += 128) od[f] = buf[0][f] + buf[1][f];
}

// ---------------------------------------------------------------------------
// K_scale2: scale[row] = g[row] / ||V[row]|| for both layers in one launch.
// ---------------------------------------------------------------------------
__global__ __launch_bounds__(256)
void k_scale2(const float* __restrict__ V0, const float* __restrict__ g0,
              const float* __restrict__ V1, const float* __restrict__ g1,
              float* __restrict__ scale0, float* __restrict__ scale1) {
  __shared__ float red[256];
  const int row = blockIdx.x;               // 0..1023
  const int t   = threadIdx.x;
  const bool first = row < 512;
  const int r = first ? row : row - 512;
  const float* vr = (first ? V0 : V1) + (size_t)r * HID;
  float s = 0.f;
  for (int k = t; k < HID; k += 256) { float v = vr[k]; s += v * v; }
  red[t] = s;
  __syncthreads();
  for (int w = 128; w > 0; w >>= 1) {
    if (t < w) red[t] += red[t + w];
    __syncthreads();
  }
  if (t == 0) {
    float g = first ? g0[r] : g1[r];
    (first ? scale0 : scale1)[r] = g / sqrtf(red[0]);
  }
}

// ---------------------------------------------------------------------------
// K_layer: hout[n][o] = act( scale[o]*dot(hrow, W[o]) + bias[o] ).
// REDUCE: hrow = (sum over SEG psum segments)/cnt (fused h0 computation).
// ---------------------------------------------------------------------------
template <bool SILU, bool SCALED, bool REDUCE>
__global__ __launch_bounds__(256)
void k_layer(const float* __restrict__ hin, const float* __restrict__ W,
             const float* __restrict__ scale, const float* __restrict__ bias,
             const int* __restrict__ cnt, float* __restrict__ hout) {
  __shared__ float hrow[HID];
  const int n = blockIdx.y;
  const int t = threadIdx.x;
  const int o = blockIdx.x * 256 + t;
  if (REDUCE) {
    float inv = 1.f / fmaxf((float)cnt[n], 1.f);
    for (int f = t; f < HID; f += 256) {
      float s = 0.f;
      for (int seg = 0; seg < SEG; ++seg)
        s += hin[((size_t)n * SEG + seg) * HID + f];
      hrow[f] = s * inv;
    }
  } else {
    for (int f = t; f < HID; f += 256) hrow[f] = hin[(size_t)n * HID + f];
  }
  __syncthreads();
  const float* wr = W + (size_t)o * HID;
  float s0 = 0.f, s1 = 0.f, s2 = 0.f, s3 = 0.f;
  for (int k = 0; k < HID; k += 4) {
    float4 h4 = *(const float4*)&hrow[k];
    float4 w4 = *(const float4*)&wr[k];
    s0 += h4.x * w4.x; s1 += h4.y * w4.y;
    s2 += h4.z * w4.z; s3 += h4.w * w4.w;
  }
  float sdot = (s0 + s1) + (s2 + s3);
  float y = SCALED ? (sdot * scale[o] + bias[o]) : (sdot + bias[o]);
  if (SILU) y = y / (1.f + expf(-y));
  hout[(size_t)n * HID + o] = y;
}

// ---------------------------------------------------------------------------
// K_scatter: natural-order broadcast; nontemporal streaming stores.
// Each block owns 128 contiguous points (256 KB of sequential stores).
// ---------------------------------------------------------------------------
__global__ __launch_bounds__(256)
void k_scatter(const int* __restrict__ cids, const float* __restrict__ h3,
               float* __restrict__ out) {
  __shared__ int cl[128];
  const int t = threadIdx.x;
  const int q = t & 127;                    // float4 index in row
  const int half = t >> 7;
  const int base = blockIdx.x * 128;
  if (t < 128) cl[t] = cids[base + t];
  __syncthreads();
  #pragma unroll 8
  for (int p = half; p < 128; p += 2) {
    int c = cl[p];
    v4f hv = ((const v4f*)(h3 + (size_t)c * HID))[q];
    v4f* dst = (v4f*)(out + (size_t)(base + p) * HID) + q;
    __builtin_nontemporal_store(hv, dst);
  }
}

// ---------------------------------------------------------------------------
extern "C" void kernel_launch(void* const* d_in, const int* in_sizes, int n_in,
                              void* d_out, int out_size, void* d_ws, size_t ws_size,
                              hipStream_t stream) {
  const float* x  = (const float*)d_in[0];
  const float* V0 = (const float*)d_in[1];
  const float* g0 = (const float*)d_in[2];
  const float* b0 = (const float*)d_in[3];
  const float* V1 = (const float*)d_in[4];
  const float* g1 = (const float*)d_in[5];
  const float* b1 = (const float*)d_in[6];
  const float* Wf = (const float*)d_in[7];
  const float* bf = (const float*)d_in[8];
  float* out = (float*)d_out;
  float* ws  = (float*)d_ws;

  size_t off = 0;
  float* psum   = ws + off; off += (size_t)NCASE * SEG * HID;
  float* h1     = ws + off; off += NCASE * HID;
  float* h2     = ws + off; off += NCASE * HID;
  float* h3     = ws + off; off += NCASE * HID;
  float* scale0 = ws + off; off += 512;
  float* scale1 = ws + off; off += 512;
  int* iws = (int*)(ws + off);
  size_t ioff = 0;
  int* hist    = iws + ioff; ioff += NCASE * NB;
  int* rel     = iws + ioff; ioff += NB * NCASE;
  int* cnt     = iws + ioff; ioff += NCASE;
  int* cids    = iws + ioff; ioff += NPTS;
  int* idxlist = iws + ioff; ioff += NPTS;

  k_scale2<<<dim3(1024), dim3(256), 0, stream>>>(V0, g0, V1, g1, scale0, scale1);
  k_hist  <<<dim3(NB), dim3(256), 0, stream>>>(x, hist, cids);
  k_scan  <<<dim3(NCASE), dim3(NB), 0, stream>>>(hist, rel, cnt);
  k_build <<<dim3(NB), dim3(64), 0, stream>>>(cids, rel, cnt, idxlist);
  k_sum   <<<dim3(SEG, NCASE), dim3(128), 0, stream>>>(x, idxlist, cnt, psum);
  k_layer<true,  true,  true ><<<dim3(2, NCASE), dim3(256), 0, stream>>>(psum, V0, scale0, b0, cnt, h1);
  k_layer<true,  true,  false><<<dim3(2, NCASE), dim3(256), 0, stream>>>(h1,   V1, scale1, b1, cnt, h2);
  k_layer<false, false, false><<<dim3(2, NCASE), dim3(256), 0, stream>>>(h2,   Wf, nullptr, bf, cnt, h3);
  k_scatter<<<dim3(NPTS / 128), dim3(256), 0, stream>>>(cids, h3, out);
}